// Round 2
// baseline (1322.583 us; speedup 1.0000x reference)
//
#include <hip/hip_runtime.h>
#include <math.h>

// SO3 DiT layer, MI355X fp32.
// Round 1: scatter->gather attention. CSR by dst built on-device, then one
// fused wave-per-dst kernel (eq GEMM + ev GEMM + online softmax + aggregate)
// with zero atomics in the hot path.

#define NN 6000
#define EE 72000

__device__ __forceinline__ float wsum(float v) {
#pragma unroll
  for (int o = 32; o >= 1; o >>= 1) v += __shfl_xor(v, o, 64);
  return v;
}
__device__ __forceinline__ int deg_of(int m) { return (m == 0) ? 0 : ((m < 4) ? 1 : 2); }

// ---------------- K1a: LayerNorm(T=64) + SiLU, one wave per node ----------------
__global__ __launch_bounds__(256) void k_ln_t(const float* __restrict__ ft,
                                              const float* __restrict__ lns,
                                              const float* __restrict__ lnb,
                                              float* __restrict__ sbuf) {
  int w = (blockIdx.x * 256 + threadIdx.x) >> 6;  // node, exact 6000
  int lane = threadIdx.x & 63;
  float t = ft[(size_t)w * 64 + lane];
  float mu = wsum(t) * (1.f / 64.f);
  float d = t - mu;
  float var = wsum(d * d) * (1.f / 64.f);
  float cin = d * rsqrtf(var + 1e-6f) * lns[lane] + lnb[lane];
  sbuf[(size_t)w * 64 + lane] = cin / (1.f + expf(-cin));
}

// ---------------- K1b: c = silu @ W_c + b_c  (64 -> 1664), 8 nodes/block ----------------
__global__ __launch_bounds__(256) void k_cond_mm(const float* __restrict__ sbuf,
                                                 const float* __restrict__ Wc,
                                                 const float* __restrict__ bc,
                                                 float* __restrict__ c) {
  int n0 = blockIdx.x * 8;  // 750 blocks
  for (int jj = threadIdx.x; jj < 1664; jj += 256) {
    float acc[8] = {0, 0, 0, 0, 0, 0, 0, 0};
#pragma unroll 8
    for (int k2 = 0; k2 < 64; k2++) {
      float wv = Wc[(size_t)k2 * 1664 + jj];
#pragma unroll
      for (int nd = 0; nd < 8; nd++) acc[nd] += sbuf[(size_t)(n0 + nd) * 64 + k2] * wv;
    }
    float b = bc[jj];
#pragma unroll
    for (int nd = 0; nd < 8; nd++) c[(size_t)(n0 + nd) * 1664 + jj] = acc[nd] + b;
  }
}

// ---------------- K2/K8: eqv layernorm + modulate, one wave per (n,p) ----------------
__global__ __launch_bounds__(256) void k_lnmod(const float* __restrict__ xin,
                                               const float* __restrict__ c,
                                               float* __restrict__ xout,
                                               int goff, int boff) {
  int w = (blockIdx.x * 256 + threadIdx.x) >> 6;  // (n,p) pair, exact 12000
  int lane = threadIdx.x & 63;
  int n = w >> 1, p = w & 1;
  const float* xb = xin + (size_t)w * 576 + lane;
  float x0 = xb[0], x1 = xb[64], x2 = xb[128], x3 = xb[192], x4 = xb[256];
  float x5 = xb[320], x6 = xb[384], x7 = xb[448], x8 = xb[512];
  float mu = wsum(x0) * (1.f / 64.f);
  x0 -= mu;
  float n20 = x0 * x0;
  float n21 = (x1 * x1 + x2 * x2 + x3 * x3) * (1.f / 3.f);
  float n22 = (x4 * x4 + x5 * x5 + x6 * x6 + x7 * x7 + x8 * x8) * (1.f / 5.f);
  n20 = wsum(n20) * (1.f / 64.f);
  n21 = wsum(n21) * (1.f / 64.f);
  n22 = wsum(n22) * (1.f / 64.f);
  float i0 = rsqrtf(n20 + 1e-6f), i1 = rsqrtf(n21 + 1e-6f), i2 = rsqrtf(n22 + 1e-6f);
  const float* cb = c + (size_t)n * 1664;
  float g0 = 1.f + cb[goff + p * 192 + lane];
  float g1 = 1.f + cb[goff + p * 192 + 64 + lane];
  float g2 = 1.f + cb[goff + p * 192 + 128 + lane];
  float bsh = cb[boff + lane];
  float* ob = xout + (size_t)w * 576 + lane;
  ob[0] = x0 * i0 * g0 + bsh;
  ob[64] = x1 * i1 * g1;
  ob[128] = x2 * i1 * g1;
  ob[192] = x3 * i1 * g1;
  ob[256] = x4 * i2 * g2;
  ob[320] = x5 * i2 * g2;
  ob[384] = x6 * i2 * g2;
  ob[448] = x7 * i2 * g2;
  ob[512] = x8 * i2 * g2;
}

// ---------------- K3: per-(p,m) 64x64 projection, weight column in VGPRs ----------------
__global__ __launch_bounds__(256) void k_rowmat(const float* __restrict__ x,
                                                const float* __restrict__ W,
                                                float* __restrict__ out) {
  int pm = blockIdx.y;
  int p = pm / 9, mm = pm % 9, dm = deg_of(mm);
  int lane = threadIdx.x & 63;
  const float* Wb = W + (size_t)(p * 3 + dm) * 4096;
  float wreg[64];
#pragma unroll
  for (int f = 0; f < 64; f++) wreg[f] = Wb[f * 64 + lane];
  int wid = __builtin_amdgcn_readfirstlane((int)((blockIdx.x * 256 + threadIdx.x) >> 6));
  int nwaves = (gridDim.x * 256) >> 6;
  for (int n = wid; n < NN; n += nwaves) {
    const float* xr = x + ((size_t)n * 18 + pm) * 64;  // uniform -> s_load
    float acc = 0.f;
#pragma unroll
    for (int f = 0; f < 64; f++) acc += xr[f] * wreg[f];
    out[((size_t)n * 18 + pm) * 64 + lane] = acc;
  }
}

// ---------------- CSR build: histogram -> scan -> scatter ----------------
__global__ __launch_bounds__(256) void k_hist(const int* __restrict__ dst_idx,
                                              int* __restrict__ deg) {
  int e = blockIdx.x * 256 + threadIdx.x;
  if (e < EE) atomicAdd(deg + dst_idx[e], 1);
}

__global__ __launch_bounds__(1024) void k_scan(const int* __restrict__ deg,
                                               int* __restrict__ row_ptr,
                                               int* __restrict__ wptr) {
  __shared__ int part[1024];
  int t = threadIdx.x;
  int base = t * 6;  // 1024*6 = 6144 >= 6000
  int loc[6];
  int s = 0;
#pragma unroll
  for (int i = 0; i < 6; i++) {
    int idx = base + i;
    int d = (idx < NN) ? deg[idx] : 0;
    loc[i] = s;
    s += d;
  }
  part[t] = s;
  __syncthreads();
  int val = s;
  for (int off = 1; off < 1024; off <<= 1) {
    int tmp = (t >= off) ? part[t - off] : 0;
    __syncthreads();
    part[t] += tmp;
    __syncthreads();
  }
  int excl = part[t] - val;
#pragma unroll
  for (int i = 0; i < 6; i++) {
    int idx = base + i;
    if (idx < NN) {
      int v = excl + loc[i];
      row_ptr[idx] = v;
      wptr[idx] = v;
    }
  }
  if (t == 1023) row_ptr[NN] = excl + val;
}

__global__ __launch_bounds__(256) void k_scatter(const int* __restrict__ src_idx,
                                                 const int* __restrict__ dst_idx,
                                                 int* __restrict__ wptr,
                                                 int* __restrict__ csr_e,
                                                 int* __restrict__ csr_src) {
  int e = blockIdx.x * 256 + threadIdx.x;
  if (e < EE) {
    int d = dst_idx[e];
    int pos = atomicAdd(wptr + d, 1);
    csr_e[pos] = e;
    csr_src[pos] = src_idx[e];
  }
}

// ---------------- K4+5+6 fused: gather attention, one wave per dst ----------------
// Per dst: loop incident edges, compute eq = fe@We_qk and ev = fe@We_v sharing
// the fe scalar loads, logit via 16-lane-group reduce, online softmax per lane
// (head = lane>>4), accumulate w*ev*v[src] into 18 registers. No atomics.
__global__ __launch_bounds__(256) void k_attn(const float* __restrict__ fe,
                                              const float* __restrict__ Weqk,
                                              const float* __restrict__ Wev,
                                              const float* __restrict__ q,
                                              const float* __restrict__ kk,
                                              const float* __restrict__ v,
                                              const float* __restrict__ cutoff,
                                              const int* __restrict__ row_ptr,
                                              const int* __restrict__ csr_e,
                                              const int* __restrict__ csr_src,
                                              float* __restrict__ attn_out,
                                              float* __restrict__ meancut) {
  int lane = threadIdx.x & 63;
  float wqk[64], wv[64];
#pragma unroll
  for (int f = 0; f < 64; f++) {
    wqk[f] = Weqk[f * 64 + lane];
    wv[f] = Wev[f * 64 + lane];
  }
  int wid = __builtin_amdgcn_readfirstlane((int)((blockIdx.x * 256 + threadIdx.x) >> 6));
  int nw = (gridDim.x * 256) >> 6;
  for (int d = wid; d < NN; d += nw) {
    int beg = __builtin_amdgcn_readfirstlane(row_ptr[d]);
    int end = __builtin_amdgcn_readfirstlane(row_ptr[d + 1]);
    const float* qb = q + (size_t)d * 1152 + lane;
    float qreg[18];
#pragma unroll
    for (int j = 0; j < 18; j++) qreg[j] = qb[j * 64];
    float acc[18];
#pragma unroll
    for (int j = 0; j < 18; j++) acc[j] = 0.f;
    float ml = -3.0e38f, dl = 0.f, cs = 0.f;
    for (int i = beg; i < end; i++) {
      int e = __builtin_amdgcn_readfirstlane(csr_e[i]);
      int s = __builtin_amdgcn_readfirstlane(csr_src[i]);
      const float* feb = fe + (size_t)e * 576;  // uniform -> s_load
      const float* kb = kk + (size_t)s * 1152 + lane;
      const float* vb = v + (size_t)s * 1152 + lane;
      float ev[9];
      float lacc = 0.f;
      for (int m = 0; m < 9; m++) {
        float eq = 0.f, evv = 0.f;
#pragma unroll
        for (int f = 0; f < 64; f++) {
          float fv = feb[m * 64 + f];
          eq += fv * wqk[f];
          evv += fv * wv[f];
        }
        ev[m] = evv;
        float qk = qreg[m] * kb[m * 64] + qreg[m + 9] * kb[m * 64 + 576];
        lacc += eq * qk;
      }
      lacc *= 0.05892556509887896f;  // 1/sqrt(P*M*DH) = 1/sqrt(288)
      lacc += __shfl_xor(lacc, 8, 64);
      lacc += __shfl_xor(lacc, 4, 64);
      lacc += __shfl_xor(lacc, 2, 64);
      lacc += __shfl_xor(lacc, 1, 64);
      // lacc is now the logit of head (lane>>4), replicated over its 16 lanes
      float co = cutoff[e];
      cs += co;
      float mnew = fmaxf(ml, lacc);
      float scale = expf(ml - mnew);
      float w = expf(lacc - mnew) * co;
      dl = dl * scale + w;
#pragma unroll
      for (int j = 0; j < 18; j++) acc[j] *= scale;
#pragma unroll
      for (int m = 0; m < 9; m++) {
        float sv = w * ev[m];
        acc[m] += sv * vb[m * 64];
        acc[m + 9] += sv * vb[m * 64 + 576];
      }
      ml = mnew;
    }
    float inv = 1.f / (dl + 1e-9f);
    float* ob = attn_out + (size_t)d * 1152 + lane;
#pragma unroll
    for (int m = 0; m < 9; m++) {
      ob[m * 64] = acc[m] * inv;
      ob[576 + m * 64] = acc[m + 9] * inv;
    }
    if (lane == 0) meancut[d] = cs / fmaxf((float)(end - beg), 1.f);
  }
}

// ---------------- K7: Wo projection + post-select + gate(a1) + residual ----------------
__global__ __launch_bounds__(256) void k_wo_post(const float* __restrict__ attn_out,
                                                 const float* __restrict__ Wo,
                                                 const float* __restrict__ xpre,
                                                 const float* __restrict__ fnodes,
                                                 const float* __restrict__ c,
                                                 const float* __restrict__ meancut,
                                                 float* __restrict__ out) {
  int pm = blockIdx.y;
  int p = pm / 9, mm = pm % 9, dm = deg_of(mm);
  int lane = threadIdx.x & 63;
  const float* Wb = Wo + (size_t)(p * 3 + dm) * 4096;
  float wreg[64];
#pragma unroll
  for (int f = 0; f < 64; f++) wreg[f] = Wb[f * 64 + lane];
  int wid = __builtin_amdgcn_readfirstlane((int)((blockIdx.x * 256 + threadIdx.x) >> 6));
  int nwaves = (gridDim.x * 256) >> 6;
  for (int n = wid; n < NN; n += nwaves) {
    const float* xr = attn_out + ((size_t)n * 18 + pm) * 64;
    float acc = 0.f;
#pragma unroll
    for (int f = 0; f < 64; f++) acc += xr[f] * wreg[f];
    float mc = meancut[n];
    size_t idx = ((size_t)n * 18 + pm) * 64 + lane;
    float post = (mc < 1e-5f) ? xpre[idx] : acc;
    float a1v = c[(size_t)n * 1664 + 448 + (p * 3 + dm) * 64 + lane];
    out[idx] = fnodes[idx] + a1v * post;
  }
}

// ---------------- K9a: h = eqv_gelu(x_pre2 @ W1), 8 nodes/block ----------------
__global__ __launch_bounds__(256) void k_mlp1(const float* __restrict__ xp2,
                                              const float* __restrict__ W1,
                                              float* __restrict__ h) {
  int n0 = blockIdx.x * 8;  // 750 blocks
  int j = threadIdx.x;
  float gate[8];
  {  // pm = 0 first: its output defines the gelu gate per column
    float acc[8] = {0, 0, 0, 0, 0, 0, 0, 0};
#pragma unroll 8
    for (int f = 0; f < 64; f++) {
      float wv = W1[(size_t)f * 256 + j];
#pragma unroll
      for (int nd = 0; nd < 8; nd++) acc[nd] += xp2[(size_t)(n0 + nd) * 1152 + f] * wv;
    }
#pragma unroll
    for (int nd = 0; nd < 8; nd++) {
      float s = acc[nd];
      float g = (fabsf(s) > 1e-4f)
                    ? 0.5f * (1.f + tanhf(0.7978845608028654f * (s + 0.044715f * s * s * s)))
                    : 0.5f;
      gate[nd] = g;
      h[(size_t)(n0 + nd) * 4608 + j] = s * g;
    }
  }
  for (int pm = 1; pm < 18; pm++) {
    int p = pm / 9, mm = pm % 9, dm = deg_of(mm);
    const float* wb = W1 + (size_t)(p * 3 + dm) * 16384;
    float acc[8] = {0, 0, 0, 0, 0, 0, 0, 0};
#pragma unroll 8
    for (int f = 0; f < 64; f++) {
      float wv = wb[(size_t)f * 256 + j];
#pragma unroll
      for (int nd = 0; nd < 8; nd++)
        acc[nd] += xp2[(size_t)(n0 + nd) * 1152 + pm * 64 + f] * wv;
    }
#pragma unroll
    for (int nd = 0; nd < 8; nd++)
      h[(size_t)(n0 + nd) * 4608 + pm * 256 + j] = acc[nd] * gate[nd];
  }
}

// ---------------- K9b: out += a2 * (h @ W2), 8 nodes/block ----------------
__global__ __launch_bounds__(256) void k_mlp2(const float* __restrict__ h,
                                              const float* __restrict__ W2,
                                              const float* __restrict__ c,
                                              float* __restrict__ out) {
  int n0 = blockIdx.x * 8;  // 750 blocks
  int g = threadIdx.x & 63;
  int pr = threadIdx.x >> 6;
  for (int pm = pr; pm < 18; pm += 4) {
    int p = pm / 9, mm = pm % 9, dm = deg_of(mm);
    const float* wb = W2 + (size_t)(p * 3 + dm) * 16384;
    float acc[8] = {0, 0, 0, 0, 0, 0, 0, 0};
#pragma unroll 8
    for (int k = 0; k < 256; k++) {
      float wv = wb[(size_t)k * 64 + g];
#pragma unroll
      for (int nd = 0; nd < 8; nd++)
        acc[nd] += h[(size_t)(n0 + nd) * 4608 + pm * 256 + k] * wv;
    }
#pragma unroll
    for (int nd = 0; nd < 8; nd++) {
      int n = n0 + nd;
      size_t idx = ((size_t)n * 18 + pm) * 64 + g;
      out[idx] += c[(size_t)n * 1664 + 1280 + (p * 3 + dm) * 64 + g] * acc[nd];
    }
  }
}

// ---------------- workspace layout (bytes) ----------------
// c:      [0, 39,936,000)                         live whole call
// xpre:   [39,936,000, 67,584,000)                x_pre then x_pre2
// k:      [67,584,000, 95,232,000)                live through k_attn
// q:      [95,232,000, 122,880,000)               live through k_attn
// v:      [122,880,000, 150,528,000)              live through k_attn
// sbuf:   [150,528,000, 152,064,000)              early only
// attn_o: [152,064,000, 179,712,000)              k_attn -> k_wo_post (dead before h)
// h:      [95,232,000, 205,824,000)               overlays q/v/sbuf/attn_o after attention
// csr tail past 205,824,000:
#define OFF_C 0UL
#define OFF_XPRE 39936000UL
#define OFF_K 67584000UL
#define OFF_Q 95232000UL
#define OFF_V 122880000UL
#define OFF_SBUF 150528000UL
#define OFF_ATTN 152064000UL
#define OFF_H 95232000UL
#define OFF_DEG 205824000UL      // 24,000
#define OFF_ROWPTR 205848000UL   // 24,004 (pad to 24,032)
#define OFF_WPTR 205872032UL     // 24,000
#define OFF_CSRE 205896032UL     // 288,000
#define OFF_CSRSRC 206184032UL   // 288,000
#define OFF_MEANCUT 206472032UL  // 24,000
#define WS_NEEDED 206496032UL

extern "C" void kernel_launch(void* const* d_in, const int* in_sizes, int n_in,
                              void* d_out, int out_size, void* d_ws, size_t ws_size,
                              hipStream_t stream) {
  const float* f_nodes = (const float*)d_in[0];
  const float* f_edges = (const float*)d_in[1];
  const float* f_time = (const float*)d_in[2];
  const float* cutoff = (const float*)d_in[3];
  const float* ln_s = (const float*)d_in[4];
  const float* ln_b = (const float*)d_in[5];
  const float* W_c = (const float*)d_in[6];
  const float* b_c = (const float*)d_in[7];
  const float* Wq = (const float*)d_in[8];
  const float* Wk = (const float*)d_in[9];
  const float* Wv = (const float*)d_in[10];
  const float* Wo = (const float*)d_in[11];
  const float* We_qk = (const float*)d_in[12];
  const float* We_v = (const float*)d_in[13];
  const float* W1 = (const float*)d_in[14];
  const float* W2 = (const float*)d_in[15];
  const int* src_idx = (const int*)d_in[16];
  const int* dst_idx = (const int*)d_in[17];
  float* out = (float*)d_out;
  char* ws = (char*)d_ws;
  if (ws_size < WS_NEEDED) return;

  float* c = (float*)(ws + OFF_C);
  float* xpre = (float*)(ws + OFF_XPRE);
  float* kbuf = (float*)(ws + OFF_K);
  float* qbuf = (float*)(ws + OFF_Q);
  float* vbuf = (float*)(ws + OFF_V);
  float* sbuf = (float*)(ws + OFF_SBUF);
  float* attn_out = (float*)(ws + OFF_ATTN);
  float* hbuf = (float*)(ws + OFF_H);
  int* deg = (int*)(ws + OFF_DEG);
  int* row_ptr = (int*)(ws + OFF_ROWPTR);
  int* wptr = (int*)(ws + OFF_WPTR);
  int* csr_e = (int*)(ws + OFF_CSRE);
  int* csr_src = (int*)(ws + OFF_CSRSRC);
  float* meancut = (float*)(ws + OFF_MEANCUT);

  // CSR build (depends only on indices; run first)
  hipMemsetAsync(ws + OFF_DEG, 0, 24000, stream);
  k_hist<<<282, 256, 0, stream>>>(dst_idx, deg);
  k_scan<<<1, 1024, 0, stream>>>(deg, row_ptr, wptr);
  k_scatter<<<282, 256, 0, stream>>>(src_idx, dst_idx, wptr, csr_e, csr_src);

  k_ln_t<<<1500, 256, 0, stream>>>(f_time, ln_s, ln_b, sbuf);
  k_cond_mm<<<750, 256, 0, stream>>>(sbuf, W_c, b_c, c);
  k_lnmod<<<3000, 256, 0, stream>>>(f_nodes, c, xpre, 0, 384);

  dim3 g94(94, 18);
  k_rowmat<<<g94, 256, 0, stream>>>(xpre, Wq, qbuf);
  k_rowmat<<<g94, 256, 0, stream>>>(xpre, Wk, kbuf);
  k_rowmat<<<g94, 256, 0, stream>>>(xpre, Wv, vbuf);

  k_attn<<<1500, 256, 0, stream>>>(f_edges, We_qk, We_v, qbuf, kbuf, vbuf, cutoff,
                                   row_ptr, csr_e, csr_src, attn_out, meancut);
  k_wo_post<<<g94, 256, 0, stream>>>(attn_out, Wo, xpre, f_nodes, c, meancut, out);

  k_lnmod<<<3000, 256, 0, stream>>>(out, c, xpre, 832, 1216);  // x_pre2
  k_mlp1<<<750, 256, 0, stream>>>(xpre, W1, hbuf);
  k_mlp2<<<750, 256, 0, stream>>>(hbuf, W2, c, out);
}